// Round 5
// baseline (262.603 us; speedup 1.0000x reference)
//
#include <hip/hip_runtime.h>
#include <hip/hip_bf16.h>

// MHA: B=2, T=2048, D=1024, H=16, Hd=64. fp32 in/out, bf16 MFMA internally.

typedef __bf16 bf16_t;
typedef __bf16 bf16x8 __attribute__((ext_vector_type(8)));
typedef __bf16 bf16x4 __attribute__((ext_vector_type(4)));
typedef __bf16 bf16x2 __attribute__((ext_vector_type(2)));
typedef short short4v __attribute__((ext_vector_type(4)));
typedef float f32x4 __attribute__((ext_vector_type(4)));
typedef unsigned int u32;

#define D_MODEL 1024
#define SEQ_T   2048
#define NHEAD   16
#define HDIM    64
#define M_ROWS  4096   // B*T
#define MEGA    (1024 * 1024)

// async global->LDS, 16B per lane; LDS dest MUST be wave-uniform base + lane*16
__device__ __forceinline__ void gl2lds16(const void* g, void* l) {
    __builtin_amdgcn_global_load_lds((const __attribute__((address_space(1))) u32*)g,
                                     (__attribute__((address_space(3))) u32*)l, 16, 0, 0);
}

__device__ __forceinline__ short4v as_s4(bf16x4 v) {
    union { bf16x4 h; short4v s; } u; u.h = v; return u.s;
}

// ---------------------------------------------------------------------------
// prep: transpose-cast 4 weights (W[k][n] fp32 -> Wt[n][k] bf16), and
// (precast path) cast q,k,v fp32 -> bf16 row-major.
// ---------------------------------------------------------------------------
__global__ __launch_bounds__(256) void prep(
    const float* __restrict__ Wq, const float* __restrict__ Wk,
    const float* __restrict__ Wv, const float* __restrict__ Wo,
    const float* __restrict__ Xq, const float* __restrict__ Xk, const float* __restrict__ Xv,
    bf16_t* __restrict__ Wqt, bf16_t* __restrict__ Wkt,
    bf16_t* __restrict__ Wvt, bf16_t* __restrict__ Wot,
    bf16_t* __restrict__ Xb)
{
    int blk = blockIdx.x, tid = threadIdx.x;
    if (blk < 4096) {
        int wi = blk >> 10, t = blk & 1023;
        int n0 = (t & 31) * 32, k0 = (t >> 5) * 32;
        const float* W = wi == 0 ? Wq : (wi == 1 ? Wk : (wi == 2 ? Wv : Wo));
        bf16_t* Wt = wi == 0 ? Wqt : (wi == 1 ? Wkt : (wi == 2 ? Wvt : Wot));
        __shared__ float tile[32][33];
        int tx = tid & 31, ty = tid >> 5;   // 32 x 8
#pragma unroll
        for (int i = 0; i < 32; i += 8)
            tile[ty + i][tx] = W[(k0 + ty + i) * D_MODEL + n0 + tx];
        __syncthreads();
#pragma unroll
        for (int i = 0; i < 32; i += 8)
            Wt[(size_t)(n0 + ty + i) * D_MODEL + k0 + tx] = (bf16_t)tile[tx][ty + i];
    } else {
        int b2 = blk - 4096;
        int xi = b2 >> 10;
        const float* X = xi == 0 ? Xq : (xi == 1 ? Xk : Xv);
        bf16_t* XB = Xb + (size_t)xi * M_ROWS * D_MODEL;
        size_t base = (size_t)(b2 & 1023) * 4096 + tid * 16;
        const float4* xp = (const float4*)(X + base);
        float4 a0 = xp[0], a1 = xp[1], a2 = xp[2], a3 = xp[3];
        bf16x8 o0, o1;
        o0[0] = (bf16_t)a0.x; o0[1] = (bf16_t)a0.y; o0[2] = (bf16_t)a0.z; o0[3] = (bf16_t)a0.w;
        o0[4] = (bf16_t)a1.x; o0[5] = (bf16_t)a1.y; o0[6] = (bf16_t)a1.z; o0[7] = (bf16_t)a1.w;
        o1[0] = (bf16_t)a2.x; o1[1] = (bf16_t)a2.y; o1[2] = (bf16_t)a2.z; o1[3] = (bf16_t)a2.w;
        o1[4] = (bf16_t)a3.x; o1[5] = (bf16_t)a3.y; o1[6] = (bf16_t)a3.z; o1[7] = (bf16_t)a3.w;
        *(bf16x8*)(XB + base) = o0;
        *(bf16x8*)(XB + base + 8) = o1;
    }
}

// ---------------------------------------------------------------------------
// Fused projection GEMM (Q,K,V): 128x128 tile, BK=64, XOR-chunk-rotated LDS,
// DOUBLE-BUFFERED: next K-tile's global_load_lds issued before computing the
// current one, single barrier per iter -> vmcnt drain overlapped with MFMA.
// Q epilogue pre-scales by 1/sqrt(Hd)=0.125.
// blockIdx.y: [0..7]=Q, [8..15]=K, [16..23]=V (V writes V^T [B,H,Hd,T]).
// ---------------------------------------------------------------------------
template <bool PRECAST>
__global__ __launch_bounds__(256) void proj_fused(
    const float* __restrict__ Xq, const float* __restrict__ Xk, const float* __restrict__ Xv,
    const bf16_t* __restrict__ Xb,
    const bf16_t* __restrict__ Wqt, const bf16_t* __restrict__ Wkt, const bf16_t* __restrict__ Wvt,
    const float* __restrict__ bq, const float* __restrict__ bk, const float* __restrict__ bv,
    bf16_t* __restrict__ Qh, bf16_t* __restrict__ Kh, bf16_t* __restrict__ Vt)
{
    __shared__ bf16_t Ab[2][128 * 64];   // 2 x 16KB
    __shared__ bf16_t Bb[2][128 * 64];   // 2 x 16KB
    int tid = threadIdx.x;
    int w = tid >> 6, lane = tid & 63, lo16 = lane & 15, quad = lane >> 4;
    int m0 = blockIdx.x * 128;
    int proj = blockIdx.y >> 3;
    int n0 = (blockIdx.y & 7) * 128;
    const float*  X    = proj == 0 ? Xq  : (proj == 1 ? Xk  : Xv);
    const bf16_t* XB   = Xb + (size_t)proj * M_ROWS * D_MODEL;
    const bf16_t* Wt   = proj == 0 ? Wqt : (proj == 1 ? Wkt : Wvt);
    const float*  bias = proj == 0 ? bq  : (proj == 1 ? bk  : bv);
    int wm = (w >> 1) * 64, wn = (w & 1) * 64;

    auto stage = [&](int buf, int k0) {
#pragma unroll
        for (int p = 0; p < 4; p++) {
            int idx = p * 256 + tid;            // 0..1023 chunks of 16B
            int row = idx >> 3, cp = idx & 7, cl = (cp - row) & 7;
            if (PRECAST) {
                gl2lds16(XB + (size_t)(m0 + row) * D_MODEL + k0 + cl * 8, Ab[buf] + idx * 8);
            } else {
                const float* as = X + (size_t)(m0 + row) * D_MODEL + k0 + cl * 8;
                float4 a0 = *(const float4*)as, a1 = *(const float4*)(as + 4);
                bf16x8 av;
                av[0] = (bf16_t)a0.x; av[1] = (bf16_t)a0.y; av[2] = (bf16_t)a0.z; av[3] = (bf16_t)a0.w;
                av[4] = (bf16_t)a1.x; av[5] = (bf16_t)a1.y; av[6] = (bf16_t)a1.z; av[7] = (bf16_t)a1.w;
                *(bf16x8*)(Ab[buf] + idx * 8) = av;
            }
            gl2lds16(Wt + (size_t)(n0 + row) * D_MODEL + k0 + cl * 8, Bb[buf] + idx * 8);
        }
    };

    f32x4 acc[4][4];
#pragma unroll
    for (int i = 0; i < 4; i++)
#pragma unroll
        for (int j = 0; j < 4; j++) acc[i][j] = (f32x4){0.f, 0.f, 0.f, 0.f};

    stage(0, 0);
    __syncthreads();
    for (int it = 0; it < 16; it++) {
        int cur = it & 1;
        if (it + 1 < 16) stage(cur ^ 1, (it + 1) * 64);
#pragma unroll
        for (int kh = 0; kh < 2; kh++) {
            bf16x8 af[4], bfr[4];
#pragma unroll
            for (int i = 0; i < 4; i++) {
                int row = wm + i * 16 + lo16;
                af[i] = *(bf16x8*)(Ab[cur] + row * 64 + (((kh * 4 + quad) + row) & 7) * 8);
            }
#pragma unroll
            for (int j = 0; j < 4; j++) {
                int row = wn + j * 16 + lo16;
                bfr[j] = *(bf16x8*)(Bb[cur] + row * 64 + (((kh * 4 + quad) + row) & 7) * 8);
            }
#pragma unroll
            for (int i = 0; i < 4; i++)
#pragma unroll
                for (int j = 0; j < 4; j++)
                    acc[i][j] = __builtin_amdgcn_mfma_f32_16x16x32_bf16(af[i], bfr[j], acc[i][j], 0, 0, 0);
        }
        __syncthreads();   // drains prefetch (issued before compute) + guards reuse
    }

    float qscale = proj == 0 ? 0.125f : 1.0f;
#pragma unroll
    for (int j = 0; j < 4; j++) {
        int col = n0 + wn + j * 16 + lo16;
        float bv2 = bias[col];
        int h = col >> 6, hd = col & 63;
#pragma unroll
        for (int i = 0; i < 4; i++) {
#pragma unroll
            for (int r = 0; r < 4; r++) {
                int m = m0 + wm + i * 16 + quad * 4 + r;
                int b = m >> 11, t = m & 2047;
                bf16_t val = (bf16_t)((acc[i][j][r] + bv2) * qscale);
                if (proj == 2)
                    Vt[(((size_t)(b * NHEAD + h) * HDIM + hd) * SEQ_T) + t] = val;
                else if (proj == 1)
                    Kh[(((size_t)(b * NHEAD + h) * SEQ_T + t) * HDIM) + hd] = val;
                else
                    Qh[(((size_t)(b * NHEAD + h) * SEQ_T + t) * HDIM) + hd] = val;
            }
        }
    }
}

// ---------------------------------------------------------------------------
// Flash attention v5: S^T = K*Q^T (P stays in registers, feeds PV as the
// B-operand of 16x16x16 MFMAs), no-max softmax (Q pre-scaled by 0.125),
// K/V LDS DOUBLE-BUFFERED with prefetch-before-compute. Block = 2 waves x
// 32 q-rows; block handles the pair (qt=31-pr, qt=pr) = exactly 33 k-tiles
// flattened into one pipelined loop. Grid 32 bh x 16 pairs = 512 blocks.
// ---------------------------------------------------------------------------
__global__ __launch_bounds__(128) void flash_attn(const bf16_t* __restrict__ Qh,
                                                  const bf16_t* __restrict__ Kh,
                                                  const bf16_t* __restrict__ Vt,
                                                  bf16_t* __restrict__ Ob) {
    int bh = blockIdx.x & 31;              // b*16 + h
    int pr = blockIdx.x >> 5;              // 0..15
    int tid = threadIdx.x;
    int w = tid >> 6, lane = tid & 63, lo16 = lane & 15, quad = lane >> 4;

    __shared__ bf16_t KL[2][64 * 64];      // 2 x 8KB, [key][chunk-rotated d]
    __shared__ bf16_t VL[2][64 * 64];      // 2 x 8KB, [d][chunk-rotated key]

    const bf16_t* Qp = Qh + (size_t)bh * SEQ_T * HDIM;
    const bf16_t* Kp = Kh + (size_t)bh * SEQ_T * HDIM;
    const bf16_t* Vp = Vt + (size_t)bh * HDIM * SEQ_T;
    int b = bh >> 4, h = bh & 15;

    auto stageKV = [&](int buf, int kt) {
#pragma unroll
        for (int p = 0; p < 4; p++) {
            int idx = p * 128 + tid;         // 512 chunks of 16B each buf
            int row = idx >> 3, cp = idx & 7, cl = (cp - row) & 7;
            gl2lds16(Kp + (size_t)(kt * 64 + row) * HDIM + cl * 8, KL[buf] + idx * 8);
            gl2lds16(Vp + (size_t)row * SEQ_T + kt * 64 + cl * 8, VL[buf] + idx * 8);
        }
    };

    int qt_hi = 31 - pr, qt_lo = pr;
    int n0t = qt_hi + 1, ntot = n0t + qt_lo + 1;   // 33 tiles total

    // mutable per-u state
    int qt_cur = qt_hi;
    int qbase = qt_cur * 64 + w * 32;
    bf16x8 qf[2][2];
    f32x4 oacc[2][4];
    float lsum[2];

    auto load_q = [&]() {
#pragma unroll
        for (int n = 0; n < 2; n++) {
            const bf16_t* qr = Qp + (size_t)(qbase + n * 16 + lo16) * HDIM;
            qf[n][0] = *(const bf16x8*)(qr + quad * 8);
            qf[n][1] = *(const bf16x8*)(qr + 32 + quad * 8);
        }
    };
    auto zero_state = [&]() {
#pragma unroll
        for (int n = 0; n < 2; n++) {
            lsum[n] = 0.f;
#pragma unroll
            for (int t = 0; t < 4; t++) oacc[n][t] = (f32x4){0.f, 0.f, 0.f, 0.f};
        }
    };
    auto epilogue = [&]() {
#pragma unroll
        for (int n = 0; n < 2; n++) {
            float lt = lsum[n];
            lt += __shfl_xor(lt, 16);
            lt += __shfl_xor(lt, 32);
            float inv = 1.f / lt;
            int q = qbase + n * 16 + lo16;
            bf16_t* dst = Ob + ((size_t)b * SEQ_T + q) * D_MODEL + h * HDIM;
#pragma unroll
            for (int t = 0; t < 4; t++) {
#pragma unroll
                for (int rp = 0; rp < 2; rp++) {
                    int d0 = t * 16 + quad * 4 + rp * 2;
                    bf16x2 pk;
                    pk[0] = (bf16_t)(oacc[n][t][rp * 2] * inv);
                    pk[1] = (bf16_t)(oacc[n][t][rp * 2 + 1] * inv);
                    *(bf16x2*)(dst + d0) = pk;
                }
            }
        }
    };

    load_q();
    zero_state();
    stageKV(0, 0);
    __syncthreads();

    for (int j = 0; j < ntot; j++) {
        int cur = j & 1;
        if (j + 1 < ntot) {
            int jn = j + 1;
            int ktn = jn < n0t ? jn : jn - n0t;
            stageKV(jn & 1, ktn);
        }
        int kt = j < n0t ? j : j - n0t;

        // K frags (A-operand), shared across both q-subtiles
        bf16x8 kf[4][2];
#pragma unroll
        for (int s = 0; s < 4; s++) {
            int keyr = s * 16 + lo16;
            kf[s][0] = *(bf16x8*)(KL[cur] + keyr * 64 + ((quad + keyr) & 7) * 8);
            kf[s][1] = *(bf16x8*)(KL[cur] + keyr * 64 + ((quad + 4 + keyr) & 7) * 8);
        }

        bool diag = (kt == qt_cur);
        short4v pf[2][4];
#pragma unroll
        for (int n = 0; n < 2; n++) {
            f32x4 sacc[4];
#pragma unroll
            for (int s = 0; s < 4; s++) sacc[s] = (f32x4){0.f, 0.f, 0.f, 0.f};
#pragma unroll
            for (int s = 0; s < 4; s++) {
                sacc[s] = __builtin_amdgcn_mfma_f32_16x16x32_bf16(kf[s][0], qf[n][0], sacc[s], 0, 0, 0);
                sacc[s] = __builtin_amdgcn_mfma_f32_16x16x32_bf16(kf[s][1], qf[n][1], sacc[s], 0, 0, 0);
            }
            int q = qbase + n * 16 + lo16;
#pragma unroll
            for (int s = 0; s < 4; s++) {
                bf16x4 pv;
#pragma unroll
                for (int r = 0; r < 4; r++) {
                    float e = __expf(sacc[s][r]);
                    if (diag) {
                        int key = kt * 64 + s * 16 + quad * 4 + r;
                        e = (key <= q) ? e : 0.f;
                    }
                    lsum[n] += e;
                    pv[r] = (bf16_t)e;
                }
                pf[n][s] = as_s4(pv);
            }
        }

        // O^T += V^T * P^T  (A = V frag from LDS, B = register P)
#pragma unroll
        for (int t = 0; t < 4; t++) {
            int drow = t * 16 + lo16;
#pragma unroll
            for (int s = 0; s < 4; s++) {
                int c = s * 16 + quad * 4;
                int phys = ((c >> 3) + drow) & 7;
                bf16x4 vf = *(bf16x4*)(VL[cur] + drow * 64 + phys * 8 + (c & 7));
                short4v vfs = as_s4(vf);
                oacc[0][t] = __builtin_amdgcn_mfma_f32_16x16x16bf16_1k(vfs, pf[0][s], oacc[0][t], 0, 0, 0);
                oacc[1][t] = __builtin_amdgcn_mfma_f32_16x16x16bf16_1k(vfs, pf[1][s], oacc[1][t], 0, 0, 0);
            }
        }

        __syncthreads();   // drains prefetch + guards buffer reuse

        if (j == n0t - 1) {           // u=0 finished: flush, switch to qt_lo
            epilogue();
            qt_cur = qt_lo;
            qbase = qt_cur * 64 + w * 32;
            load_q();
            zero_state();
        }
    }
    epilogue();
}

// ---------------------------------------------------------------------------
// Output GEMM: out(fp32) = Ob(bf16) @ Wot^T + bo. 128x128 tile, BK=64,
// rotated + DOUBLE-BUFFERED LDS (64KB). Grid (32,8)=256 blocks = 1/CU,
// so prefetch-before-compute is the only latency hiding available.
// ---------------------------------------------------------------------------
__global__ __launch_bounds__(256) void out_gemm(const bf16_t* __restrict__ A,
                                                const bf16_t* __restrict__ Wt,
                                                const float* __restrict__ bias,
                                                float* __restrict__ out) {
    __shared__ bf16_t Ab[2][128 * 64];   // 2 x 16KB
    __shared__ bf16_t Bb[2][128 * 64];   // 2 x 16KB
    int tid = threadIdx.x;
    int w = tid >> 6, lane = tid & 63, lo16 = lane & 15, quad = lane >> 4;
    int m0 = blockIdx.x * 128;
    int n0 = blockIdx.y * 128;
    int wm = (w >> 1) * 64, wn = (w & 1) * 64;

    auto stage = [&](int buf, int k0) {
#pragma unroll
        for (int p = 0; p < 4; p++) {
            int idx = p * 256 + tid;
            int row = idx >> 3, cp = idx & 7, cl = (cp - row) & 7;
            gl2lds16(A  + (size_t)(m0 + row) * D_MODEL + k0 + cl * 8, Ab[buf] + idx * 8);
            gl2lds16(Wt + (size_t)(n0 + row) * D_MODEL + k0 + cl * 8, Bb[buf] + idx * 8);
        }
    };

    f32x4 acc[4][4];
#pragma unroll
    for (int i = 0; i < 4; i++)
#pragma unroll
        for (int j = 0; j < 4; j++) acc[i][j] = (f32x4){0.f, 0.f, 0.f, 0.f};

    stage(0, 0);
    __syncthreads();
    for (int it = 0; it < 16; it++) {
        int cur = it & 1;
        if (it + 1 < 16) stage(cur ^ 1, (it + 1) * 64);
#pragma unroll
        for (int kh = 0; kh < 2; kh++) {
            bf16x8 af[4], bfr[4];
#pragma unroll
            for (int i = 0; i < 4; i++) {
                int row = wm + i * 16 + lo16;
                af[i] = *(bf16x8*)(Ab[cur] + row * 64 + (((kh * 4 + quad) + row) & 7) * 8);
            }
#pragma unroll
            for (int j = 0; j < 4; j++) {
                int row = wn + j * 16 + lo16;
                bfr[j] = *(bf16x8*)(Bb[cur] + row * 64 + (((kh * 4 + quad) + row) & 7) * 8);
            }
#pragma unroll
            for (int i = 0; i < 4; i++)
#pragma unroll
                for (int j = 0; j < 4; j++)
                    acc[i][j] = __builtin_amdgcn_mfma_f32_16x16x32_bf16(af[i], bfr[j], acc[i][j], 0, 0, 0);
        }
        __syncthreads();
    }

#pragma unroll
    for (int j = 0; j < 4; j++) {
        int col = n0 + wn + j * 16 + lo16;
        float bv2 = bias[col];
#pragma unroll
        for (int i = 0; i < 4; i++)
#pragma unroll
            for (int r = 0; r < 4; r++) {
                int m = m0 + wm + i * 16 + quad * 4 + r;
                out[(size_t)m * D_MODEL + col] = acc[i][j][r] + bv2;
            }
    }
}

// ---------------------------------------------------------------------------
extern "C" void kernel_launch(void* const* d_in, const int* in_sizes, int n_in,
                              void* d_out, int out_size, void* d_ws, size_t ws_size,
                              hipStream_t stream) {
    const float* q  = (const float*)d_in[0];
    const float* k  = (const float*)d_in[1];
    const float* v  = (const float*)d_in[2];
    const float* Wq = (const float*)d_in[3];
    const float* bq = (const float*)d_in[4];
    const float* Wk = (const float*)d_in[5];
    const float* bk = (const float*)d_in[6];
    const float* Wv = (const float*)d_in[7];
    const float* bv = (const float*)d_in[8];
    const float* Wo = (const float*)d_in[9];
    const float* bo = (const float*)d_in[10];
    float* out = (float*)d_out;

    // ws layout (bf16 elems): 4 weights (4M) + Qh/Kh/Vt (12M) + Xb|Ob (12M|4M).
    bf16_t* Wqt = (bf16_t*)d_ws;
    bf16_t* Wkt = Wqt + (size_t)MEGA;
    bf16_t* Wvt = Wkt + (size_t)MEGA;
    bf16_t* Wot = Wvt + (size_t)MEGA;
    bf16_t* Qh  = Wot + (size_t)MEGA;                // [B,H,T,Hd]
    bf16_t* Kh  = Qh  + (size_t)M_ROWS * D_MODEL;
    bf16_t* Vt  = Kh  + (size_t)M_ROWS * D_MODEL;    // [B,H,Hd,T]
    bf16_t* Xb  = Vt  + (size_t)M_ROWS * D_MODEL;    // 3 x [4096,1024] bf16
    bf16_t* Ob  = Xb;                                // [B,T,D] (aliases Xb)

    bool precast = ws_size >= (size_t)(4 * MEGA + 6 * M_ROWS * D_MODEL) * sizeof(bf16_t);

    int prep_blocks = precast ? 4096 + 3 * 1024 : 4096;
    prep<<<prep_blocks, 256, 0, stream>>>(Wq, Wk, Wv, Wo, q, k, v, Wqt, Wkt, Wvt, Wot, Xb);

    dim3 pg(M_ROWS / 128, 24);   // y: 0..7 Q, 8..15 K, 16..23 V
    if (precast)
        proj_fused<true><<<pg, 256, 0, stream>>>(q, k, v, Xb, Wqt, Wkt, Wvt, bq, bk, bv, Qh, Kh, Vt);
    else
        proj_fused<false><<<pg, 256, 0, stream>>>(q, k, v, Xb, Wqt, Wkt, Wvt, bq, bk, bv, Qh, Kh, Vt);

    flash_attn<<<32 * 16, 128, 0, stream>>>(Qh, Kh, Vt, Ob);

    dim3 og(M_ROWS / 128, D_MODEL / 128);
    out_gemm<<<og, 256, 0, stream>>>(Ob, Wot, bo, out);
}

// Round 6
// 229.589 us; speedup vs baseline: 1.1438x; 1.1438x over previous
//
#include <hip/hip_runtime.h>
#include <hip/hip_bf16.h>

// MHA: B=2, T=2048, D=1024, H=16, Hd=64. fp32 in/out, bf16 MFMA internally.

typedef __bf16 bf16_t;
typedef __bf16 bf16x8 __attribute__((ext_vector_type(8)));
typedef __bf16 bf16x4 __attribute__((ext_vector_type(4)));
typedef __bf16 bf16x2 __attribute__((ext_vector_type(2)));
typedef short short4v __attribute__((ext_vector_type(4)));
typedef float f32x4 __attribute__((ext_vector_type(4)));
typedef unsigned int u32;

#define D_MODEL 1024
#define SEQ_T   2048
#define NHEAD   16
#define HDIM    64
#define M_ROWS  4096   // B*T
#define MEGA    (1024 * 1024)

// async global->LDS, 16B per lane; LDS dest MUST be wave-uniform base + lane*16
__device__ __forceinline__ void gl2lds16(const void* g, void* l) {
    __builtin_amdgcn_global_load_lds((const __attribute__((address_space(1))) u32*)g,
                                     (__attribute__((address_space(3))) u32*)l, 16, 0, 0);
}

__device__ __forceinline__ short4v as_s4(bf16x4 v) {
    union { bf16x4 h; short4v s; } u; u.h = v; return u.s;
}

// ---------------------------------------------------------------------------
// prep: blocks [0,1024): 64x64 transpose-cast tiles of the 4 weights
// (W[k][n] fp32 -> Wt[n][k] bf16). blocks [1024,1024+1536): cast q,k,v
// fp32 -> bf16 row-major, 32 floats/thread.
// ---------------------------------------------------------------------------
__global__ __launch_bounds__(256) void prep(
    const float* __restrict__ Wq, const float* __restrict__ Wk,
    const float* __restrict__ Wv, const float* __restrict__ Wo,
    const float* __restrict__ Xq, const float* __restrict__ Xk, const float* __restrict__ Xv,
    bf16_t* __restrict__ Wqt, bf16_t* __restrict__ Wkt,
    bf16_t* __restrict__ Wvt, bf16_t* __restrict__ Wot,
    bf16_t* __restrict__ Xb)
{
    int blk = blockIdx.x, tid = threadIdx.x;
    if (blk < 1024) {
        int wi = blk >> 8, t = blk & 255;
        int n0 = (t & 15) * 64, k0 = (t >> 4) * 64;
        const float* W = wi == 0 ? Wq : (wi == 1 ? Wk : (wi == 2 ? Wv : Wo));
        bf16_t* Wt = wi == 0 ? Wqt : (wi == 1 ? Wkt : (wi == 2 ? Wvt : Wot));
        __shared__ float tile[64][65];
        int tx = tid & 63, ty = tid >> 6;   // 64 x 4
#pragma unroll
        for (int i = 0; i < 64; i += 4)
            tile[ty + i][tx] = W[(k0 + ty + i) * D_MODEL + n0 + tx];
        __syncthreads();
#pragma unroll
        for (int i = 0; i < 64; i += 4)
            Wt[(size_t)(n0 + ty + i) * D_MODEL + k0 + tx] = (bf16_t)tile[tx][ty + i];
    } else {
        int b2 = blk - 1024;
        int xi = b2 >> 9;                  // /512
        const float* X = xi == 0 ? Xq : (xi == 1 ? Xk : Xv);
        bf16_t* XB = Xb + (size_t)xi * M_ROWS * D_MODEL;
        size_t base = (size_t)(b2 & 511) * 8192 + tid * 32;
#pragma unroll
        for (int half = 0; half < 2; half++) {
            const float4* xp = (const float4*)(X + base + half * 16);
            float4 a0 = xp[0], a1 = xp[1], a2 = xp[2], a3 = xp[3];
            bf16x8 o0, o1;
            o0[0] = (bf16_t)a0.x; o0[1] = (bf16_t)a0.y; o0[2] = (bf16_t)a0.z; o0[3] = (bf16_t)a0.w;
            o0[4] = (bf16_t)a1.x; o0[5] = (bf16_t)a1.y; o0[6] = (bf16_t)a1.z; o0[7] = (bf16_t)a1.w;
            o1[0] = (bf16_t)a2.x; o1[1] = (bf16_t)a2.y; o1[2] = (bf16_t)a2.z; o1[3] = (bf16_t)a2.w;
            o1[4] = (bf16_t)a3.x; o1[5] = (bf16_t)a3.y; o1[6] = (bf16_t)a3.z; o1[7] = (bf16_t)a3.w;
            *(bf16x8*)(XB + base + half * 16) = o0;
            *(bf16x8*)(XB + base + half * 16 + 8) = o1;
        }
    }
}

// ---------------------------------------------------------------------------
// Fused projection GEMM (Q,K,V): 128x128 tile, BK=32, SINGLE-buffered LDS
// (m97 structure — multi-block wave overlap does the latency hiding),
// 4-chunk XOR rotation (residual 2-way conflict = free).
// Q epilogue pre-scales by 1/sqrt(Hd)=0.125.
// blockIdx.y: [0..7]=Q, [8..15]=K, [16..23]=V (V writes V^T [B,H,Hd,T]).
// ---------------------------------------------------------------------------
template <bool PRECAST>
__global__ __launch_bounds__(256) void proj_fused(
    const float* __restrict__ Xq, const float* __restrict__ Xk, const float* __restrict__ Xv,
    const bf16_t* __restrict__ Xb,
    const bf16_t* __restrict__ Wqt, const bf16_t* __restrict__ Wkt, const bf16_t* __restrict__ Wvt,
    const float* __restrict__ bq, const float* __restrict__ bk, const float* __restrict__ bv,
    bf16_t* __restrict__ Qh, bf16_t* __restrict__ Kh, bf16_t* __restrict__ Vt)
{
    __shared__ bf16_t Ab[128 * 32];   // 8KB, [row][4 chunks rotated by row]
    __shared__ bf16_t Bb[128 * 32];   // 8KB
    int tid = threadIdx.x;
    int w = tid >> 6, lane = tid & 63, lo16 = lane & 15, quad = lane >> 4;
    int m0 = blockIdx.x * 128;
    int proj = blockIdx.y >> 3;
    int n0 = (blockIdx.y & 7) * 128;
    const float*  X    = proj == 0 ? Xq  : (proj == 1 ? Xk  : Xv);
    const bf16_t* XB   = Xb + (size_t)proj * M_ROWS * D_MODEL;
    const bf16_t* Wt   = proj == 0 ? Wqt : (proj == 1 ? Wkt : Wvt);
    const float*  bias = proj == 0 ? bq  : (proj == 1 ? bk  : bv);
    int wm = (w >> 1) * 64, wn = (w & 1) * 64;

    f32x4 acc[4][4];
#pragma unroll
    for (int i = 0; i < 4; i++)
#pragma unroll
        for (int j = 0; j < 4; j++) acc[i][j] = (f32x4){0.f, 0.f, 0.f, 0.f};

    for (int k0 = 0; k0 < D_MODEL; k0 += 32) {
        __syncthreads();
#pragma unroll
        for (int p = 0; p < 2; p++) {
            int idx = p * 256 + tid;            // 0..511 chunks of 16B
            int row = idx >> 2, cp = idx & 3, cl = (cp - row) & 3;
            if (PRECAST) {
                gl2lds16(XB + (size_t)(m0 + row) * D_MODEL + k0 + cl * 8, Ab + idx * 8);
            } else {
                const float* as = X + (size_t)(m0 + row) * D_MODEL + k0 + cl * 8;
                float4 a0 = *(const float4*)as, a1 = *(const float4*)(as + 4);
                bf16x8 av;
                av[0] = (bf16_t)a0.x; av[1] = (bf16_t)a0.y; av[2] = (bf16_t)a0.z; av[3] = (bf16_t)a0.w;
                av[4] = (bf16_t)a1.x; av[5] = (bf16_t)a1.y; av[6] = (bf16_t)a1.z; av[7] = (bf16_t)a1.w;
                *(bf16x8*)(Ab + idx * 8) = av;
            }
            gl2lds16(Wt + (size_t)(n0 + row) * D_MODEL + k0 + cl * 8, Bb + idx * 8);
        }
        __syncthreads();
        bf16x8 af[4], bfr[4];
#pragma unroll
        for (int i = 0; i < 4; i++) {
            int row = wm + i * 16 + lo16;
            af[i] = *(bf16x8*)(Ab + row * 32 + ((quad + row) & 3) * 8);
        }
#pragma unroll
        for (int j = 0; j < 4; j++) {
            int row = wn + j * 16 + lo16;
            bfr[j] = *(bf16x8*)(Bb + row * 32 + ((quad + row) & 3) * 8);
        }
#pragma unroll
        for (int i = 0; i < 4; i++)
#pragma unroll
            for (int j = 0; j < 4; j++)
                acc[i][j] = __builtin_amdgcn_mfma_f32_16x16x32_bf16(af[i], bfr[j], acc[i][j], 0, 0, 0);
    }

    float qscale = proj == 0 ? 0.125f : 1.0f;
#pragma unroll
    for (int j = 0; j < 4; j++) {
        int col = n0 + wn + j * 16 + lo16;
        float bv2 = bias[col];
        int h = col >> 6, hd = col & 63;
#pragma unroll
        for (int i = 0; i < 4; i++) {
#pragma unroll
            for (int r = 0; r < 4; r++) {
                int m = m0 + wm + i * 16 + quad * 4 + r;
                int b = m >> 11, t = m & 2047;
                bf16_t val = (bf16_t)((acc[i][j][r] + bv2) * qscale);
                if (proj == 2)
                    Vt[(((size_t)(b * NHEAD + h) * HDIM + hd) * SEQ_T) + t] = val;
                else if (proj == 1)
                    Kh[(((size_t)(b * NHEAD + h) * SEQ_T + t) * HDIM) + hd] = val;
                else
                    Qh[(((size_t)(b * NHEAD + h) * SEQ_T + t) * HDIM) + hd] = val;
            }
        }
    }
}

// ---------------------------------------------------------------------------
// Flash attention v6: 4 waves/block sharing one K/V staging (halves LDS-DMA
// per wave), each wave owns 16 q-rows of a 64-row q-tile. S^T = K*Q^T keeps
// P in registers (C-layout == 16x16x16 B-operand layout). No-max softmax
// (Q pre-scaled by 0.125). Pair-balanced: block handles (qt=31-pr, qt=pr)
// = exactly 33 k-tiles. K/V double-buffered (2x8KB each). Grid 32x16=512
// blocks x 4 waves = 8 waves/CU.
// ---------------------------------------------------------------------------
__global__ __launch_bounds__(256) void flash_attn(const bf16_t* __restrict__ Qh,
                                                  const bf16_t* __restrict__ Kh,
                                                  const bf16_t* __restrict__ Vt,
                                                  bf16_t* __restrict__ Ob) {
    int bh = blockIdx.x & 31;              // b*16 + h
    int pr = blockIdx.x >> 5;              // 0..15
    int tid = threadIdx.x;
    int w = tid >> 6, lane = tid & 63, lo16 = lane & 15, quad = lane >> 4;

    __shared__ bf16_t KL[2][64 * 64];      // [key][chunk-rotated d]
    __shared__ bf16_t VL[2][64 * 64];      // [d][chunk-rotated key]

    const bf16_t* Qp = Qh + (size_t)bh * SEQ_T * HDIM;
    const bf16_t* Kp = Kh + (size_t)bh * SEQ_T * HDIM;
    const bf16_t* Vp = Vt + (size_t)bh * HDIM * SEQ_T;
    int b = bh >> 4, h = bh & 15;

    auto stageKV = [&](int buf, int kt) {
#pragma unroll
        for (int p = 0; p < 2; p++) {
            int idx = p * 256 + tid;         // 512 chunks of 16B each buf
            int row = idx >> 3, cp = idx & 7, cl = (cp - row) & 7;
            gl2lds16(Kp + (size_t)(kt * 64 + row) * HDIM + cl * 8, KL[buf] + idx * 8);
            gl2lds16(Vp + (size_t)row * SEQ_T + kt * 64 + cl * 8, VL[buf] + idx * 8);
        }
    };

    int qt_hi = 31 - pr, qt_lo = pr;
    int n0t = qt_hi + 1, ntot = n0t + qt_lo + 1;   // 33 tiles total

    int qt_cur = qt_hi;
    int qbase = qt_cur * 64 + w * 16;
    bf16x8 qf0, qf1;
    f32x4 oacc[4];
    float lsum;

    auto load_q = [&]() {
        const bf16_t* qr = Qp + (size_t)(qbase + lo16) * HDIM;
        qf0 = *(const bf16x8*)(qr + quad * 8);
        qf1 = *(const bf16x8*)(qr + 32 + quad * 8);
    };
    auto zero_state = [&]() {
        lsum = 0.f;
#pragma unroll
        for (int t = 0; t < 4; t++) oacc[t] = (f32x4){0.f, 0.f, 0.f, 0.f};
    };
    auto epilogue = [&]() {
        float lt = lsum;
        lt += __shfl_xor(lt, 16);
        lt += __shfl_xor(lt, 32);
        float inv = 1.f / lt;
        int q = qbase + lo16;
        bf16_t* dst = Ob + ((size_t)b * SEQ_T + q) * D_MODEL + h * HDIM;
#pragma unroll
        for (int t = 0; t < 4; t++) {
#pragma unroll
            for (int rp = 0; rp < 2; rp++) {
                int d0 = t * 16 + quad * 4 + rp * 2;
                bf16x2 pk;
                pk[0] = (bf16_t)(oacc[t][rp * 2] * inv);
                pk[1] = (bf16_t)(oacc[t][rp * 2 + 1] * inv);
                *(bf16x2*)(dst + d0) = pk;
            }
        }
    };

    load_q();
    zero_state();
    stageKV(0, 0);
    __syncthreads();

    for (int j = 0; j < ntot; j++) {
        int cur = j & 1;
        if (j + 1 < ntot) {
            int jn = j + 1;
            int ktn = jn < n0t ? jn : jn - n0t;
            stageKV(jn & 1, ktn);
        }
        int kt = j < n0t ? j : j - n0t;

        // K frags (A-operand of S^T)
        bf16x8 kf[4][2];
#pragma unroll
        for (int s = 0; s < 4; s++) {
            int keyr = s * 16 + lo16;
            kf[s][0] = *(bf16x8*)(KL[cur] + keyr * 64 + ((quad + keyr) & 7) * 8);
            kf[s][1] = *(bf16x8*)(KL[cur] + keyr * 64 + ((quad + 4 + keyr) & 7) * 8);
        }

        // S^T = K * Q^T  -> C-layout: col=q (lane&15), row=key (quad*4+r)
        f32x4 sacc[4];
#pragma unroll
        for (int s = 0; s < 4; s++) sacc[s] = (f32x4){0.f, 0.f, 0.f, 0.f};
#pragma unroll
        for (int s = 0; s < 4; s++) {
            sacc[s] = __builtin_amdgcn_mfma_f32_16x16x32_bf16(kf[s][0], qf0, sacc[s], 0, 0, 0);
            sacc[s] = __builtin_amdgcn_mfma_f32_16x16x32_bf16(kf[s][1], qf1, sacc[s], 0, 0, 0);
        }

        bool diag = (kt == qt_cur);
        int q = qbase + lo16;
        short4v pf[4];
#pragma unroll
        for (int s = 0; s < 4; s++) {
            bf16x4 pv;
#pragma unroll
            for (int r = 0; r < 4; r++) {
                float e = __expf(sacc[s][r]);
                if (diag) {
                    int key = kt * 64 + s * 16 + quad * 4 + r;
                    e = (key <= q) ? e : 0.f;
                }
                lsum += e;
                pv[r] = (bf16_t)e;
            }
            pf[s] = as_s4(pv);
        }

        // O^T += V^T * P^T  (A = V frag from LDS, B = register P)
#pragma unroll
        for (int t = 0; t < 4; t++) {
            int drow = t * 16 + lo16;
#pragma unroll
            for (int s = 0; s < 4; s++) {
                int c = s * 16 + quad * 4;
                int phys = ((c >> 3) + drow) & 7;
                bf16x4 vf = *(bf16x4*)(VL[cur] + drow * 64 + phys * 8 + (c & 7));
                oacc[t] = __builtin_amdgcn_mfma_f32_16x16x16bf16_1k(as_s4(vf), pf[s], oacc[t], 0, 0, 0);
            }
        }

        __syncthreads();   // guards buffer reuse (prefetch already in flight)

        if (j == n0t - 1) {           // qt_hi finished: flush, switch to qt_lo
            epilogue();
            qt_cur = qt_lo;
            qbase = qt_cur * 64 + w * 16;
            load_q();
            zero_state();
        }
    }
    epilogue();
}

// ---------------------------------------------------------------------------
// Output GEMM: out(fp32) = Ob(bf16) @ Wot^T + bo. 64x128 tile, BK=32,
// single-buffered rotated LDS. Grid (64,8)=512 blocks = 2/CU.
// Waves 2x2: each 32(m) x 64(n).
// ---------------------------------------------------------------------------
__global__ __launch_bounds__(256) void out_gemm(const bf16_t* __restrict__ A,
                                                const bf16_t* __restrict__ Wt,
                                                const float* __restrict__ bias,
                                                float* __restrict__ out) {
    __shared__ bf16_t Ab[64 * 32];    // 4KB
    __shared__ bf16_t Bb[128 * 32];   // 8KB
    int tid = threadIdx.x;
    int w = tid >> 6, lane = tid & 63, lo16 = lane & 15, quad = lane >> 4;
    int m0 = blockIdx.x * 64;
    int n0 = blockIdx.y * 128;
    int wm = (w >> 1) * 32, wn = (w & 1) * 64;

    f32x4 acc[2][4];
#pragma unroll
    for (int i = 0; i < 2; i++)
#pragma unroll
        for (int j = 0; j < 4; j++) acc[i][j] = (f32x4){0.f, 0.f, 0.f, 0.f};

    for (int k0 = 0; k0 < D_MODEL; k0 += 32) {
        __syncthreads();
        {
            int idx = tid;                      // 256 chunks for A (64x32)
            int row = idx >> 2, cp = idx & 3, cl = (cp - row) & 3;
            gl2lds16(A + (size_t)(m0 + row) * D_MODEL + k0 + cl * 8, Ab + idx * 8);
        }
#pragma unroll
        for (int p = 0; p < 2; p++) {
            int idx = p * 256 + tid;            // 512 chunks for B (128x32)
            int row = idx >> 2, cp = idx & 3, cl = (cp - row) & 3;
            gl2lds16(Wt + (size_t)(n0 + row) * D_MODEL + k0 + cl * 8, Bb + idx * 8);
        }
        __syncthreads();
        bf16x8 af[2], bfr[4];
#pragma unroll
        for (int i = 0; i < 2; i++) {
            int row = wm + i * 16 + lo16;
            af[i] = *(bf16x8*)(Ab + row * 32 + ((quad + row) & 3) * 8);
        }
#pragma unroll
        for (int j = 0; j < 4; j++) {
            int row = wn + j * 16 + lo16;
            bfr[j] = *(bf16x8*)(Bb + row * 32 + ((quad + row) & 3) * 8);
        }
#pragma unroll
        for (int i = 0; i < 2; i++)
#pragma unroll
            for (int j = 0; j < 4; j++)
                acc[i][j] = __builtin_amdgcn_mfma_f32_16x16x32_bf16(af[i], bfr[j], acc[i][j], 0, 0, 0);
    }

#pragma unroll
    for (int j = 0; j < 4; j++) {
        int col = n0 + wn + j * 16 + lo16;
        float bv2 = bias[col];
#pragma unroll
        for (int i = 0; i < 2; i++)
#pragma unroll
            for (int r = 0; r < 4; r++) {
                int m = m0 + wm + i * 16 + quad * 4 + r;
                out[(size_t)m * D_MODEL + col] = acc[i][j][r] + bv2;
            }
    }
}

// ---------------------------------------------------------------------------
extern "C" void kernel_launch(void* const* d_in, const int* in_sizes, int n_in,
                              void* d_out, int out_size, void* d_ws, size_t ws_size,
                              hipStream_t stream) {
    const float* q  = (const float*)d_in[0];
    const float* k  = (const float*)d_in[1];
    const float* v  = (const float*)d_in[2];
    const float* Wq = (const float*)d_in[3];
    const float* bq = (const float*)d_in[4];
    const float* Wk = (const float*)d_in[5];
    const float* bk = (const float*)d_in[6];
    const float* Wv = (const float*)d_in[7];
    const float* bv = (const float*)d_in[8];
    const float* Wo = (const float*)d_in[9];
    const float* bo = (const float*)d_in[10];
    float* out = (float*)d_out;

    // ws layout (bf16 elems): 4 weights (4M) + Qh/Kh/Vt (12M) + Xb|Ob (12M|4M).
    bf16_t* Wqt = (bf16_t*)d_ws;
    bf16_t* Wkt = Wqt + (size_t)MEGA;
    bf16_t* Wvt = Wkt + (size_t)MEGA;
    bf16_t* Wot = Wvt + (size_t)MEGA;
    bf16_t* Qh  = Wot + (size_t)MEGA;                // [B,H,T,Hd]
    bf16_t* Kh  = Qh  + (size_t)M_ROWS * D_MODEL;
    bf16_t* Vt  = Kh  + (size_t)M_ROWS * D_MODEL;    // [B,H,Hd,T]
    bf16_t* Xb  = Vt  + (size_t)M_ROWS * D_MODEL;    // 3 x [4096,1024] bf16
    bf16_t* Ob  = Xb;                                // [B,T,D] (aliases Xb)

    bool precast = ws_size >= (size_t)(4 * MEGA + 6 * M_ROWS * D_MODEL) * sizeof(bf16_t);

    int prep_blocks = precast ? 1024 + 3 * 512 : 1024;
    prep<<<prep_blocks, 256, 0, stream>>>(Wq, Wk, Wv, Wo, q, k, v, Wqt, Wkt, Wvt, Wot, Xb);

    dim3 pg(M_ROWS / 128, 24);   // y: 0..7 Q, 8..15 K, 16..23 V
    if (precast)
        proj_fused<true><<<pg, 256, 0, stream>>>(q, k, v, Xb, Wqt, Wkt, Wvt, bq, bk, bv, Qh, Kh, Vt);
    else
        proj_fused<false><<<pg, 256, 0, stream>>>(q, k, v, Xb, Wqt, Wkt, Wvt, bq, bk, bv, Qh, Kh, Vt);

    flash_attn<<<32 * 16, 256, 0, stream>>>(Qh, Kh, Vt, Ob);

    dim3 og(M_ROWS / 64, D_MODEL / 128);
    out_gemm<<<og, 256, 0, stream>>>(Ob, Wot, bo, out);
}